// Round 2
// baseline (462.329 us; speedup 1.0000x reference)
//
#include <hip/hip_runtime.h>

constexpr int NB    = 8;     // batches
constexpr int NN    = 256;   // sequence length
constexpr int F0    = 512;
constexpr int F1    = 256;
constexpr int F2    = 128;
constexpr int ROWS  = NB * NN;   // 2048
constexpr int KMAX  = 30;
constexpr float INF = 1e30f;

// ---------------- fp32 GEMM: C = act(A @ B + bias), 64x32 tile, BK=16 ----------
__global__ __launch_bounds__(256) void gemm_bias_act(
    const float* __restrict__ A, const float* __restrict__ B,
    const float* __restrict__ bias, float* __restrict__ C,
    int M, int Ncols, int K, int relu)
{
  __shared__ float As[16][64];   // [k][m]
  __shared__ float Bs[16][32];   // [k][n]
  const int tid = threadIdx.x;
  const int tx = tid & 15;       // col group  (2 cols)
  const int ty = tid >> 4;       // row group  (4 rows)
  const int rowBase = blockIdx.y * 64;
  const int colBase = blockIdx.x * 32;
  float acc[4][2] = {};
  for (int k0 = 0; k0 < K; k0 += 16) {
    {
      const int r  = tid >> 2;
      const int kq = (tid & 3) << 2;
      const float4 av = *(const float4*)(A + (size_t)(rowBase + r) * K + (k0 + kq));
      As[kq+0][r] = av.x; As[kq+1][r] = av.y; As[kq+2][r] = av.z; As[kq+3][r] = av.w;
      const int kr = tid >> 4;
      const int c2 = (tid & 15) << 1;
      const float2 bv = *(const float2*)(B + (size_t)(k0 + kr) * Ncols + (colBase + c2));
      Bs[kr][c2+0] = bv.x; Bs[kr][c2+1] = bv.y;
    }
    __syncthreads();
    #pragma unroll
    for (int kk = 0; kk < 16; kk++) {
      const float4 a = *(const float4*)&As[kk][ty*4];
      const float b0v = Bs[kk][tx*2+0];
      const float b1v = Bs[kk][tx*2+1];
      acc[0][0] += a.x*b0v; acc[0][1] += a.x*b1v;
      acc[1][0] += a.y*b0v; acc[1][1] += a.y*b1v;
      acc[2][0] += a.z*b0v; acc[2][1] += a.z*b1v;
      acc[3][0] += a.w*b0v; acc[3][1] += a.w*b1v;
    }
    __syncthreads();
  }
  #pragma unroll
  for (int i = 0; i < 4; i++) {
    const int rr = rowBase + ty*4 + i;
    #pragma unroll
    for (int j = 0; j < 2; j++) {
      const int cc = colBase + tx*2 + j;
      float v = acc[i][j] + bias[cc];
      if (relu) v = fmaxf(v, 0.0f);
      C[(size_t)rr * Ncols + cc] = v;
    }
  }
}

// ---------------- row norms: norms[r] = ||z_r||^2, one wave per row ------------
__global__ __launch_bounds__(256) void row_norms(
    const float* __restrict__ z, float* __restrict__ norms)
{
  const int wave = (blockIdx.x * blockDim.x + threadIdx.x) >> 6;
  const int lane = threadIdx.x & 63;
  if (wave >= ROWS) return;
  const float* p = z + (size_t)wave * F2;
  float a = p[lane], b = p[lane + 64];
  float v = a*a + b*b;
  #pragma unroll
  for (int d = 32; d; d >>= 1) v += __shfl_xor(v, d);
  if (lane == 0) norms[wave] = v;
}

// ---------------- D[b,n,m] = 0.5*(1 - (z_n.z_m)/sqrt(max(|z_n|^2|z_m|^2,1e-8)))
__global__ __launch_bounds__(256) void corr_dist(
    const float* __restrict__ z, const float* __restrict__ norms,
    float* __restrict__ D)
{
  const int b = blockIdx.z;
  const float* zb = z + (size_t)b * NN * F2;
  __shared__ float As[16][64];  // [k][row]
  __shared__ float Bs[16][64];  // [k][col]
  const int tid = threadIdx.x;
  const int tx = tid & 15;
  const int ty = tid >> 4;
  const int rowBase = blockIdx.y * 64;
  const int colBase = blockIdx.x * 64;
  float acc[4][4] = {};
  for (int k0 = 0; k0 < F2; k0 += 16) {
    {
      const int r  = tid >> 2;
      const int kq = (tid & 3) << 2;
      const float4 av = *(const float4*)(zb + (size_t)(rowBase + r) * F2 + (k0 + kq));
      As[kq+0][r] = av.x; As[kq+1][r] = av.y; As[kq+2][r] = av.z; As[kq+3][r] = av.w;
      const float4 bv = *(const float4*)(zb + (size_t)(colBase + r) * F2 + (k0 + kq));
      Bs[kq+0][r] = bv.x; Bs[kq+1][r] = bv.y; Bs[kq+2][r] = bv.z; Bs[kq+3][r] = bv.w;
    }
    __syncthreads();
    #pragma unroll
    for (int kk = 0; kk < 16; kk++) {
      const float4 a = *(const float4*)&As[kk][ty*4];
      const float4 bq = *(const float4*)&Bs[kk][tx*4];
      const float ar[4] = {a.x, a.y, a.z, a.w};
      const float br[4] = {bq.x, bq.y, bq.z, bq.w};
      #pragma unroll
      for (int i = 0; i < 4; i++)
        #pragma unroll
        for (int j = 0; j < 4; j++)
          acc[i][j] += ar[i] * br[j];
    }
    __syncthreads();
  }
  float* Db = D + (size_t)b * NN * NN;
  #pragma unroll
  for (int i = 0; i < 4; i++) {
    const int rr = rowBase + ty*4 + i;
    const float nr = norms[b*NN + rr];
    #pragma unroll
    for (int j = 0; j < 4; j++) {
      const int cc = colBase + tx*4 + j;
      const float nc = norms[b*NN + cc];
      const float denom = sqrtf(fmaxf(nr * nc, 1e-8f));
      Db[(size_t)rr * NN + cc] = 0.5f * (1.0f - acc[i][j] / denom);
    }
  }
}

// ---------------- row-wise fp64 inclusive scan: one wave per row ----------------
__global__ __launch_bounds__(256) void rowscan(
    const float* __restrict__ D, double* __restrict__ S)
{
  const int r = blockIdx.x * 4 + (threadIdx.x >> 6);   // 2048 rows
  const int lane = threadIdx.x & 63;
  const float4 dv = *(const float4*)(D + (size_t)r * NN + lane * 4);
  double d0 = dv.x, d1 = dv.y, d2 = dv.z, d3 = dv.w;
  double p0 = d0, p1 = p0 + d1, p2 = p1 + d2, p3 = p2 + d3;  // local inclusive
  double t = p3;
  #pragma unroll
  for (int d = 1; d < 64; d <<= 1) {
    double u = __shfl_up(t, d);
    if (lane >= d) t += u;
  }
  const double off = t - p3;                 // exclusive prefix of lane totals
  double* srow = S + (size_t)r * NN + lane * 4;
  srow[0] = off + p0; srow[1] = off + p1; srow[2] = off + p2; srow[3] = off + p3;
}

// ---------------- column-wise fp64 scan (in place): 32 blocks x 64 thr ---------
__global__ __launch_bounds__(64) void colscan(double* __restrict__ S)
{
  const int b  = blockIdx.x >> 2;
  const int j  = (blockIdx.x & 3) * 64 + threadIdx.x;
  double* p = S + (size_t)b * NN * NN + j;
  double sum = 0.0;
  for (int r = 0; r < NN; r += 8) {
    double v0 = p[(size_t)(r+0)*NN], v1 = p[(size_t)(r+1)*NN];
    double v2 = p[(size_t)(r+2)*NN], v3 = p[(size_t)(r+3)*NN];
    double v4 = p[(size_t)(r+4)*NN], v5 = p[(size_t)(r+5)*NN];
    double v6 = p[(size_t)(r+6)*NN], v7 = p[(size_t)(r+7)*NN];
    v0 += sum; v1 += v0; v2 += v1; v3 += v2; v4 += v3; v5 += v4; v6 += v5; v7 += v6;
    p[(size_t)(r+0)*NN] = v0; p[(size_t)(r+1)*NN] = v1;
    p[(size_t)(r+2)*NN] = v2; p[(size_t)(r+3)*NN] = v3;
    p[(size_t)(r+4)*NN] = v4; p[(size_t)(r+5)*NN] = v5;
    p[(size_t)(r+6)*NN] = v6; p[(size_t)(r+7)*NN] = v7;
    sum = v7;
  }
}

// ---------------- Ds -> A (shifted), C0: one block per batch -------------------
// Ds[n,j] (j>=n) = S[j][j] - 2*S[n-1][j] + S[n-1][n-1];  A[n][j+1] = Ds[n][j]
// A[n][0] = INF;  C0[n] = Ds[n][N-1]
__global__ __launch_bounds__(1024) void ds_mat(
    const double* __restrict__ S, float* __restrict__ A, float* __restrict__ C0b)
{
  const int b = blockIdx.x;
  const double* Sb = S + (size_t)b * NN * NN;
  float* Ab = A + (size_t)b * NN * NN;
  const int tid = threadIdx.x;
  const int w = tid >> 6, lane = tid & 63;
  __shared__ double diag[NN];
  if (tid < NN) diag[tid] = Sb[(size_t)tid * NN + tid];
  __syncthreads();
  for (int t = 0; t < 16; t++) {
    const int n = w * 16 + t;
    const double snn = (n > 0) ? diag[n-1] : 0.0;
    const double* srow = Sb + (size_t)(n > 0 ? n-1 : 0) * NN;
    #pragma unroll
    for (int c = 0; c < 4; c++) {
      const int j = c * 64 + lane;
      float ds = INF;
      if (j >= n) {
        const double sv = (n > 0) ? srow[j] : 0.0;
        ds = (float)(diag[j] - 2.0 * sv + snn);
      }
      if (j < NN - 1) Ab[(size_t)n * NN + j + 1] = ds;
      else            C0b[b * NN + n] = ds;       // Ds[n][N-1]
      if (j == 0)     Ab[(size_t)n * NN + 0] = INF;
    }
  }
}

// ---------------- min-plus MM: C = P (x) Q, 64x64 tile, per batch --------------
__global__ __launch_bounds__(256) void mp_mm(
    const float* __restrict__ P, const float* __restrict__ Q, float* __restrict__ Cm)
{
  const int b = blockIdx.z;
  const float* Pb = P + (size_t)b * NN * NN;
  const float* Qb = Q + (size_t)b * NN * NN;
  __shared__ float As[16][64];
  __shared__ float Bs[16][64];
  const int tid = threadIdx.x;
  const int tx = tid & 15;
  const int ty = tid >> 4;
  const int rowBase = blockIdx.y * 64;
  const int colBase = blockIdx.x * 64;
  float acc[4][4];
  #pragma unroll
  for (int i = 0; i < 4; i++)
    #pragma unroll
    for (int j = 0; j < 4; j++) acc[i][j] = INF;
  for (int k0 = 0; k0 < NN; k0 += 16) {
    {
      const int r  = tid >> 2;
      const int kq = (tid & 3) << 2;
      const float4 av = *(const float4*)(Pb + (size_t)(rowBase + r) * NN + (k0 + kq));
      As[kq+0][r] = av.x; As[kq+1][r] = av.y; As[kq+2][r] = av.z; As[kq+3][r] = av.w;
      const int kr = tid >> 4;
      const int c4 = (tid & 15) << 2;
      const float4 bv = *(const float4*)(Qb + (size_t)(k0 + kr) * NN + (colBase + c4));
      Bs[kr][c4+0] = bv.x; Bs[kr][c4+1] = bv.y; Bs[kr][c4+2] = bv.z; Bs[kr][c4+3] = bv.w;
    }
    __syncthreads();
    #pragma unroll
    for (int kk = 0; kk < 16; kk++) {
      const float4 a = *(const float4*)&As[kk][ty*4];
      const float4 bq = *(const float4*)&Bs[kk][tx*4];
      const float ar[4] = {a.x, a.y, a.z, a.w};
      const float br[4] = {bq.x, bq.y, bq.z, bq.w};
      #pragma unroll
      for (int i = 0; i < 4; i++)
        #pragma unroll
        for (int j = 0; j < 4; j++)
          acc[i][j] = fminf(acc[i][j], ar[i] + br[j]);
    }
    __syncthreads();
  }
  float* Cb = Cm + (size_t)b * NN * NN;
  #pragma unroll
  for (int i = 0; i < 4; i++)
    #pragma unroll
    for (int j = 0; j < 4; j++)
      Cb[(size_t)(rowBase + ty*4 + i) * NN + (colBase + tx*4 + j)] =
          fminf(acc[i][j], INF);
}

// ---------------- build C_0..C_31 via A, A^2, A^4: one block per batch ---------
constexpr int CS = NN + 1;   // LDS stride (bank-conflict pad)
__global__ __launch_bounds__(1024) void cchain(
    const float* __restrict__ A, const float* __restrict__ A2,
    const float* __restrict__ A4, const float* __restrict__ C0b,
    float* __restrict__ Cstk)
{
  const int b = blockIdx.x;
  const int tid = threadIdx.x;
  __shared__ float cs[32 * CS];
  __shared__ float part[1024];
  float* Ck = Cstk + (size_t)b * 32 * NN;

  if (tid < NN) { float v = C0b[b * NN + tid]; cs[0 * CS + tid] = v; Ck[0 * NN + tid] = v; }
  __syncthreads();

  // C1 = A (x) C0 : 4 partials per row
  {
    const int n = tid >> 2, q = tid & 3;
    const float* Ar = A + (size_t)b * NN * NN + (size_t)n * NN;
    float m = INF;
    for (int i = q * 64; i < q * 64 + 64; i++) m = fminf(m, Ar[i] + cs[0 * CS + i]);
    part[tid] = m;
  }
  __syncthreads();
  if (tid < NN) {
    float m = fminf(fminf(part[tid*4+0], part[tid*4+1]), fminf(part[tid*4+2], part[tid*4+3]));
    m = fminf(m, INF);
    cs[1 * CS + tid] = m; Ck[1 * NN + tid] = m;
  }
  __syncthreads();

  // [C2,C3] = A^2 (x) [C0,C1] : 2 partials per (row, v)
  {
    const int n = tid >> 2, v = (tid >> 1) & 1, qh = tid & 1;
    const float* Ar = A2 + (size_t)b * NN * NN + (size_t)n * NN;
    const float* c = &cs[v * CS];
    float m = INF;
    for (int i = qh * 128; i < qh * 128 + 128; i++) m = fminf(m, Ar[i] + c[i]);
    part[tid] = m;
  }
  __syncthreads();
  if (tid < 512) {
    const int n = tid >> 1, v = tid & 1;
    float m = fminf(part[n*4 + v*2 + 0], part[n*4 + v*2 + 1]);
    m = fminf(m, INF);
    cs[(2 + v) * CS + n] = m; Ck[(2 + v) * NN + n] = m;
  }
  __syncthreads();

  // [C_{4t+4..4t+7}] = A^4 (x) [C_{4t..4t+3}]
  const int n = tid >> 2, v = tid & 3;
  const float* Ar4 = A4 + (size_t)b * NN * NN + (size_t)n * NN;
  for (int t = 0; t < 7; t++) {
    const float* c = &cs[(4*t + v) * CS];
    float m = INF;
    for (int i = 0; i < NN; i++) m = fminf(m, Ar4[i] + c[i]);
    m = fminf(m, INF);
    const int ko = 4*t + 4 + v;
    cs[ko * CS + n] = m; Ck[ko * NN + n] = m;
    __syncthreads();
  }
}

// ---------------- out init: k=0 contribution -----------------------------------
__global__ __launch_bounds__(256) void out_init(float* __restrict__ out)
{
  const int idx = blockIdx.x * 256 + threadIdx.x;
  out[idx] = ((idx & 255) == NN - 1) ? 1.0f : 0.0f;
}

// ---------------- softmax accumulate: one block per (k, b) ---------------------
// Ds[n][i] = A[n][i+1];  anchor m_n = C_k[n];  csh[i] = C_{k-1}[i+1]
__global__ __launch_bounds__(256) void softmax_acc(
    const float* __restrict__ A, const float* __restrict__ Cstk,
    float* __restrict__ out)
{
  const int k = blockIdx.x + 1;        // 1..29
  const int b = blockIdx.y;
  const int limit = NN - k;
  const int tid = threadIdx.x;
  const float* Ab = A + (size_t)b * NN * NN;
  const float* Ckb = Cstk + (size_t)b * 32 * NN;
  __shared__ float csh[NN];    // C_{k-1}[i+1]
  __shared__ float mrow[NN];   // C_k[n]
  __shared__ float invs[NN];
  csh[tid]  = (tid < NN - 1) ? Ckb[(k - 1) * NN + tid + 1] : 0.0f;
  mrow[tid] = Ckb[k * NN + tid];
  __syncthreads();

  // pass 1: row sums
  if (tid < limit) {
    const int nrow = tid;
    const float m = mrow[nrow];
    const float* dsr = Ab + (size_t)nrow * NN + 1;   // dsr[i] = Ds[n][i]
    float s = 0.0f;
    for (int i = nrow; i < limit; i++)
      s += __expf(m - dsr[i] - csh[i]);
    invs[nrow] = 1.0f / s;
  }
  __syncthreads();

  // pass 2: column accumulation (coalesced across j)
  const int j = tid;
  if (j < limit) {
    const float cj = csh[j];
    const int nmax = (j < limit - 1) ? j : limit - 1;
    float a = 0.0f;
    for (int nr = 0; nr <= nmax; nr++)
      a += __expf(mrow[nr] - Ab[(size_t)nr * NN + j + 1] - cj) * invs[nr];
    int kmaxj = NN - 1 - j; if (kmaxj > KMAX - 1) kmaxj = KMAX - 1;
    const float cnt = (float)((j + 1) * kmaxj);
    atomicAdd(&out[b * NN + j], a / cnt);
  }
}

extern "C" void kernel_launch(void* const* d_in, const int* in_sizes, int n_in,
                              void* d_out, int out_size, void* d_ws, size_t ws_size,
                              hipStream_t stream) {
  const float* x  = (const float*)d_in[0];
  const float* W0 = (const float*)d_in[1];
  const float* b0 = (const float*)d_in[2];
  const float* W1 = (const float*)d_in[3];
  const float* b1 = (const float*)d_in[4];
  float* out = (float*)d_out;

  // ws layout (8 MiB + 8 KiB), regions reused across lifetimes:
  // [0,4M):   h (gemms) -> S fp64 (scans) -> A4 @0 (2M) + Cstk @2M (256K)
  // [4M,6M):  z (1M) + norms (8K) -> A (2M)
  // [6M,8M):  D (2M) -> A2 (2M)
  // [8M,+8K): C0buf
  char* base = (char*)d_ws;
  float*  h    = (float*)(base);
  double* S    = (double*)(base);
  float*  A4   = (float*)(base);
  float*  Cstk = (float*)(base + (2u << 20));
  float*  z    = (float*)(base + (4u << 20));
  float*  norms= (float*)(base + (5u << 20));
  float*  A    = (float*)(base + (4u << 20));
  float*  D    = (float*)(base + (6u << 20));
  float*  A2   = (float*)(base + (6u << 20));
  float*  C0b  = (float*)(base + (8u << 20));

  gemm_bias_act<<<dim3(F1/32, ROWS/64), 256, 0, stream>>>(x, W0, b0, h, ROWS, F1, F0, 1);
  gemm_bias_act<<<dim3(F2/32, ROWS/64), 256, 0, stream>>>(h, W1, b1, z, ROWS, F2, F1, 0);
  row_norms<<<dim3(ROWS*64/256), 256, 0, stream>>>(z, norms);
  corr_dist<<<dim3(NN/64, NN/64, NB), 256, 0, stream>>>(z, norms, D);
  rowscan<<<dim3(ROWS/4), 256, 0, stream>>>(D, S);
  colscan<<<dim3(NB*4), 64, 0, stream>>>(S);
  ds_mat<<<dim3(NB), 1024, 0, stream>>>(S, A, C0b);
  mp_mm<<<dim3(NN/64, NN/64, NB), 256, 0, stream>>>(A, A, A2);
  mp_mm<<<dim3(NN/64, NN/64, NB), 256, 0, stream>>>(A2, A2, A4);
  cchain<<<dim3(NB), 1024, 0, stream>>>(A, A2, A4, C0b, Cstk);
  out_init<<<dim3(ROWS/256), 256, 0, stream>>>(out);
  softmax_acc<<<dim3(KMAX-1, NB), 256, 0, stream>>>(A, Cstk, out);
}

// Round 3
// 325.381 us; speedup vs baseline: 1.4209x; 1.4209x over previous
//
#include <hip/hip_runtime.h>

constexpr int NB    = 8;     // batches
constexpr int NN    = 256;   // sequence length
constexpr int F0    = 512;
constexpr int F1    = 256;
constexpr int F2    = 128;
constexpr int ROWS  = NB * NN;   // 2048
constexpr int KMAX  = 30;
constexpr float INF = 1e30f;

// ---------------- fp32 GEMM: C = act(A @ B + bias), 64x32 tile, BK=16 ----------
__global__ __launch_bounds__(256) void gemm_bias_act(
    const float* __restrict__ A, const float* __restrict__ B,
    const float* __restrict__ bias, float* __restrict__ C,
    int M, int Ncols, int K, int relu)
{
  __shared__ float As[16][64];   // [k][m]
  __shared__ float Bs[16][32];   // [k][n]
  const int tid = threadIdx.x;
  const int tx = tid & 15;       // col group  (2 cols)
  const int ty = tid >> 4;       // row group  (4 rows)
  const int rowBase = blockIdx.y * 64;
  const int colBase = blockIdx.x * 32;
  float acc[4][2] = {};
  for (int k0 = 0; k0 < K; k0 += 16) {
    {
      const int r  = tid >> 2;
      const int kq = (tid & 3) << 2;
      const float4 av = *(const float4*)(A + (size_t)(rowBase + r) * K + (k0 + kq));
      As[kq+0][r] = av.x; As[kq+1][r] = av.y; As[kq+2][r] = av.z; As[kq+3][r] = av.w;
      const int kr = tid >> 4;
      const int c2 = (tid & 15) << 1;
      const float2 bv = *(const float2*)(B + (size_t)(k0 + kr) * Ncols + (colBase + c2));
      Bs[kr][c2+0] = bv.x; Bs[kr][c2+1] = bv.y;
    }
    __syncthreads();
    #pragma unroll
    for (int kk = 0; kk < 16; kk++) {
      const float4 a = *(const float4*)&As[kk][ty*4];
      const float b0v = Bs[kk][tx*2+0];
      const float b1v = Bs[kk][tx*2+1];
      acc[0][0] += a.x*b0v; acc[0][1] += a.x*b1v;
      acc[1][0] += a.y*b0v; acc[1][1] += a.y*b1v;
      acc[2][0] += a.z*b0v; acc[2][1] += a.z*b1v;
      acc[3][0] += a.w*b0v; acc[3][1] += a.w*b1v;
    }
    __syncthreads();
  }
  #pragma unroll
  for (int i = 0; i < 4; i++) {
    const int rr = rowBase + ty*4 + i;
    #pragma unroll
    for (int j = 0; j < 2; j++) {
      const int cc = colBase + tx*2 + j;
      float v = acc[i][j] + bias[cc];
      if (relu) v = fmaxf(v, 0.0f);
      C[(size_t)rr * Ncols + cc] = v;
    }
  }
}

// ---------------- row norms: norms[r] = ||z_r||^2, one wave per row ------------
__global__ __launch_bounds__(256) void row_norms(
    const float* __restrict__ z, float* __restrict__ norms)
{
  const int wave = (blockIdx.x * blockDim.x + threadIdx.x) >> 6;
  const int lane = threadIdx.x & 63;
  if (wave >= ROWS) return;
  const float* p = z + (size_t)wave * F2;
  float a = p[lane], b = p[lane + 64];
  float v = a*a + b*b;
  #pragma unroll
  for (int d = 32; d; d >>= 1) v += __shfl_xor(v, d);
  if (lane == 0) norms[wave] = v;
}

// ---------------- D[b,n,m] = 0.5*(1 - (z_n.z_m)/sqrt(max(|z_n|^2|z_m|^2,1e-8)))
__global__ __launch_bounds__(256) void corr_dist(
    const float* __restrict__ z, const float* __restrict__ norms,
    float* __restrict__ D)
{
  const int b = blockIdx.z;
  const float* zb = z + (size_t)b * NN * F2;
  __shared__ float As[16][64];  // [k][row]
  __shared__ float Bs[16][64];  // [k][col]
  const int tid = threadIdx.x;
  const int tx = tid & 15;
  const int ty = tid >> 4;
  const int rowBase = blockIdx.y * 64;
  const int colBase = blockIdx.x * 64;
  float acc[4][4] = {};
  for (int k0 = 0; k0 < F2; k0 += 16) {
    {
      const int r  = tid >> 2;
      const int kq = (tid & 3) << 2;
      const float4 av = *(const float4*)(zb + (size_t)(rowBase + r) * F2 + (k0 + kq));
      As[kq+0][r] = av.x; As[kq+1][r] = av.y; As[kq+2][r] = av.z; As[kq+3][r] = av.w;
      const float4 bv = *(const float4*)(zb + (size_t)(colBase + r) * F2 + (k0 + kq));
      Bs[kq+0][r] = bv.x; Bs[kq+1][r] = bv.y; Bs[kq+2][r] = bv.z; Bs[kq+3][r] = bv.w;
    }
    __syncthreads();
    #pragma unroll
    for (int kk = 0; kk < 16; kk++) {
      const float4 a = *(const float4*)&As[kk][ty*4];
      const float4 bq = *(const float4*)&Bs[kk][tx*4];
      const float ar[4] = {a.x, a.y, a.z, a.w};
      const float br[4] = {bq.x, bq.y, bq.z, bq.w};
      #pragma unroll
      for (int i = 0; i < 4; i++)
        #pragma unroll
        for (int j = 0; j < 4; j++)
          acc[i][j] += ar[i] * br[j];
    }
    __syncthreads();
  }
  float* Db = D + (size_t)b * NN * NN;
  #pragma unroll
  for (int i = 0; i < 4; i++) {
    const int rr = rowBase + ty*4 + i;
    const float nr = norms[b*NN + rr];
    #pragma unroll
    for (int j = 0; j < 4; j++) {
      const int cc = colBase + tx*4 + j;
      const float nc = norms[b*NN + cc];
      const float denom = sqrtf(fmaxf(nr * nc, 1e-8f));
      Db[(size_t)rr * NN + cc] = 0.5f * (1.0f - acc[i][j] / denom);
    }
  }
}

// ---------------- row-wise fp64 inclusive scan: one wave per row ----------------
__global__ __launch_bounds__(256) void rowscan(
    const float* __restrict__ D, double* __restrict__ S)
{
  const int r = blockIdx.x * 4 + (threadIdx.x >> 6);   // 2048 rows
  const int lane = threadIdx.x & 63;
  const float4 dv = *(const float4*)(D + (size_t)r * NN + lane * 4);
  double d0 = dv.x, d1 = dv.y, d2 = dv.z, d3 = dv.w;
  double p0 = d0, p1 = p0 + d1, p2 = p1 + d2, p3 = p2 + d3;  // local inclusive
  double t = p3;
  #pragma unroll
  for (int d = 1; d < 64; d <<= 1) {
    double u = __shfl_up(t, d);
    if (lane >= d) t += u;
  }
  const double off = t - p3;                 // exclusive prefix of lane totals
  double* srow = S + (size_t)r * NN + lane * 4;
  srow[0] = off + p0; srow[1] = off + p1; srow[2] = off + p2; srow[3] = off + p3;
}

// ---------------- column-wise fp64 scan (in place): 32 blocks x 64 thr ---------
__global__ __launch_bounds__(64) void colscan(double* __restrict__ S)
{
  const int b  = blockIdx.x >> 2;
  const int j  = (blockIdx.x & 3) * 64 + threadIdx.x;
  double* p = S + (size_t)b * NN * NN + j;
  double sum = 0.0;
  for (int r = 0; r < NN; r += 8) {
    double v0 = p[(size_t)(r+0)*NN], v1 = p[(size_t)(r+1)*NN];
    double v2 = p[(size_t)(r+2)*NN], v3 = p[(size_t)(r+3)*NN];
    double v4 = p[(size_t)(r+4)*NN], v5 = p[(size_t)(r+5)*NN];
    double v6 = p[(size_t)(r+6)*NN], v7 = p[(size_t)(r+7)*NN];
    v0 += sum; v1 += v0; v2 += v1; v3 += v2; v4 += v3; v5 += v4; v6 += v5; v7 += v6;
    p[(size_t)(r+0)*NN] = v0; p[(size_t)(r+1)*NN] = v1;
    p[(size_t)(r+2)*NN] = v2; p[(size_t)(r+3)*NN] = v3;
    p[(size_t)(r+4)*NN] = v4; p[(size_t)(r+5)*NN] = v5;
    p[(size_t)(r+6)*NN] = v6; p[(size_t)(r+7)*NN] = v7;
    sum = v7;
  }
}

// ---------------- Ds -> A (shifted), C0: one block per batch -------------------
// Ds[n,j] (j>=n) = S[j][j] - 2*S[n-1][j] + S[n-1][n-1];  A[n][j+1] = Ds[n][j]
// A[n][0] = INF;  C0[n] = Ds[n][N-1]
__global__ __launch_bounds__(1024) void ds_mat(
    const double* __restrict__ S, float* __restrict__ A, float* __restrict__ C0b)
{
  const int b = blockIdx.x;
  const double* Sb = S + (size_t)b * NN * NN;
  float* Ab = A + (size_t)b * NN * NN;
  const int tid = threadIdx.x;
  const int w = tid >> 6, lane = tid & 63;
  __shared__ double diag[NN];
  if (tid < NN) diag[tid] = Sb[(size_t)tid * NN + tid];
  __syncthreads();
  for (int t = 0; t < 16; t++) {
    const int n = w * 16 + t;
    const double snn = (n > 0) ? diag[n-1] : 0.0;
    const double* srow = Sb + (size_t)(n > 0 ? n-1 : 0) * NN;
    #pragma unroll
    for (int c = 0; c < 4; c++) {
      const int j = c * 64 + lane;
      float ds = INF;
      if (j >= n) {
        const double sv = (n > 0) ? srow[j] : 0.0;
        ds = (float)(diag[j] - 2.0 * sv + snn);
      }
      if (j < NN - 1) Ab[(size_t)n * NN + j + 1] = ds;
      else            C0b[b * NN + n] = ds;       // Ds[n][N-1]
      if (j == 0)     Ab[(size_t)n * NN + 0] = INF;
    }
  }
}

// ---------------- min-plus MM: C = P (x) Q, 64x64 tile, per batch --------------
// P, Q strictly upper triangular (INF below): skip lower tiles + clamp k range.
__global__ __launch_bounds__(256) void mp_mm(
    const float* __restrict__ P, const float* __restrict__ Q, float* __restrict__ Cm)
{
  const int b = blockIdx.z;
  const int tid = threadIdx.x;
  const int tx = tid & 15;
  const int ty = tid >> 4;
  const int rowBase = blockIdx.y * 64;
  const int colBase = blockIdx.x * 64;
  float* Cb = Cm + (size_t)b * NN * NN;
  if (colBase < rowBase) {             // strictly-lower tile: all INF
    #pragma unroll
    for (int i = 0; i < 4; i++)
      #pragma unroll
      for (int j = 0; j < 4; j++)
        Cb[(size_t)(rowBase + ty*4 + i) * NN + (colBase + tx*4 + j)] = INF;
    return;
  }
  const float* Pb = P + (size_t)b * NN * NN;
  const float* Qb = Q + (size_t)b * NN * NN;
  __shared__ float As[16][64];
  __shared__ float Bs[16][64];
  float acc[4][4];
  #pragma unroll
  for (int i = 0; i < 4; i++)
    #pragma unroll
    for (int j = 0; j < 4; j++) acc[i][j] = INF;
  const int kHi = (colBase + 64 < NN) ? colBase + 64 : NN;
  for (int k0 = rowBase; k0 < kHi; k0 += 16) {
    {
      const int r  = tid >> 2;
      const int kq = (tid & 3) << 2;
      const float4 av = *(const float4*)(Pb + (size_t)(rowBase + r) * NN + (k0 + kq));
      As[kq+0][r] = av.x; As[kq+1][r] = av.y; As[kq+2][r] = av.z; As[kq+3][r] = av.w;
      const int kr = tid >> 4;
      const int c4 = (tid & 15) << 2;
      const float4 bv = *(const float4*)(Qb + (size_t)(k0 + kr) * NN + (colBase + c4));
      Bs[kr][c4+0] = bv.x; Bs[kr][c4+1] = bv.y; Bs[kr][c4+2] = bv.z; Bs[kr][c4+3] = bv.w;
    }
    __syncthreads();
    #pragma unroll
    for (int kk = 0; kk < 16; kk++) {
      const float4 a = *(const float4*)&As[kk][ty*4];
      const float4 bq = *(const float4*)&Bs[kk][tx*4];
      const float ar[4] = {a.x, a.y, a.z, a.w};
      const float br[4] = {bq.x, bq.y, bq.z, bq.w};
      #pragma unroll
      for (int i = 0; i < 4; i++)
        #pragma unroll
        for (int j = 0; j < 4; j++)
          acc[i][j] = fminf(acc[i][j], ar[i] + br[j]);
    }
    __syncthreads();
  }
  #pragma unroll
  for (int i = 0; i < 4; i++)
    #pragma unroll
    for (int j = 0; j < 4; j++)
      Cb[(size_t)(rowBase + ty*4 + i) * NN + (colBase + tx*4 + j)] =
          fminf(acc[i][j], INF);
}

// ---------------- chain step: C_{kout+v} = P (x) C_{kin+v}, v < W --------------
// grid (4 rowgroups, NB) x 256 threads; thread = (row n, k-chunk q of 64)
constexpr int CSTR = 260;   // LDS stride: 16B-aligned, breaks pow2 banks
template<int W>
__global__ __launch_bounds__(256) void chain_step(
    const float* __restrict__ P, float* __restrict__ Cstk, int kin, int kout)
{
  const int b = blockIdx.y;
  const int tid = threadIdx.x;
  __shared__ float cs[4 * CSTR];
  #pragma unroll
  for (int v = 0; v < W; v++)
    cs[v * CSTR + tid] = Cstk[((size_t)b * 32 + kin + v) * NN + tid];
  __syncthreads();
  const int n = blockIdx.x * 64 + (tid >> 2);
  const int q = tid & 3;
  const float* Pr = P + (size_t)b * NN * NN + (size_t)n * NN + q * 64;
  float m[W];
  #pragma unroll
  for (int v = 0; v < W; v++) m[v] = INF;
  #pragma unroll 4
  for (int i = 0; i < 16; i++) {
    const float4 a = *(const float4*)(Pr + i * 4);
    #pragma unroll
    for (int v = 0; v < W; v++) {
      const float4 c = *(const float4*)&cs[v * CSTR + q * 64 + i * 4];
      m[v] = fminf(m[v], fminf(fminf(a.x + c.x, a.y + c.y),
                               fminf(a.z + c.z, a.w + c.w)));
    }
  }
  #pragma unroll
  for (int v = 0; v < W; v++) {
    m[v] = fminf(m[v], __shfl_xor(m[v], 1));
    m[v] = fminf(m[v], __shfl_xor(m[v], 2));
  }
  if (q == 0) {
    #pragma unroll
    for (int v = 0; v < W; v++)
      Cstk[((size_t)b * 32 + kout + v) * NN + n] = fminf(m[v], INF);
  }
}

// ---------------- out init (k=0 term) + C0 copy into Cstk ----------------------
__global__ __launch_bounds__(256) void out_init_c0(
    const float* __restrict__ C0b, float* __restrict__ Cstk,
    float* __restrict__ out)
{
  const int idx = blockIdx.x * 256 + threadIdx.x;       // 0..2047
  out[idx] = ((idx & 255) == NN - 1) ? 1.0f : 0.0f;
  const int b = idx >> 8, n = idx & 255;
  Cstk[(size_t)b * 32 * NN + n] = C0b[idx];
}

// ---------------- softmax accumulate: one block per (k, b) ---------------------
// Ds[n][i] = A[n][i+1];  anchor m_n = C_k[n];  csh[i] = C_{k-1}[i+1]
__global__ __launch_bounds__(256) void softmax_acc(
    const float* __restrict__ A, const float* __restrict__ Cstk,
    float* __restrict__ out)
{
  const int k = blockIdx.x + 1;        // 1..29
  const int b = blockIdx.y;
  const int limit = NN - k;
  const int tid = threadIdx.x;
  const float* Ab = A + (size_t)b * NN * NN;
  const float* Ckb = Cstk + (size_t)b * 32 * NN;
  __shared__ float csh[NN];    // C_{k-1}[i+1]
  __shared__ float mrow[NN];   // C_k[n]
  __shared__ float invs[NN];
  csh[tid]  = (tid < NN - 1) ? Ckb[(k - 1) * NN + tid + 1] : 0.0f;
  mrow[tid] = Ckb[k * NN + tid];
  __syncthreads();

  // pass 1: row sums
  if (tid < limit) {
    const int nrow = tid;
    const float m = mrow[nrow];
    const float* dsr = Ab + (size_t)nrow * NN + 1;   // dsr[i] = Ds[n][i]
    float s = 0.0f;
    for (int i = nrow; i < limit; i++)
      s += __expf(m - dsr[i] - csh[i]);
    invs[nrow] = 1.0f / s;
  }
  __syncthreads();

  // pass 2: column accumulation (coalesced across j)
  const int j = tid;
  if (j < limit) {
    const float cj = csh[j];
    const int nmax = (j < limit - 1) ? j : limit - 1;
    float a = 0.0f;
    for (int nr = 0; nr <= nmax; nr++)
      a += __expf(mrow[nr] - Ab[(size_t)nr * NN + j + 1] - cj) * invs[nr];
    int kmaxj = NN - 1 - j; if (kmaxj > KMAX - 1) kmaxj = KMAX - 1;
    const float cnt = (float)((j + 1) * kmaxj);
    atomicAdd(&out[b * NN + j], a / cnt);
  }
}

extern "C" void kernel_launch(void* const* d_in, const int* in_sizes, int n_in,
                              void* d_out, int out_size, void* d_ws, size_t ws_size,
                              hipStream_t stream) {
  const float* x  = (const float*)d_in[0];
  const float* W0 = (const float*)d_in[1];
  const float* b0 = (const float*)d_in[2];
  const float* W1 = (const float*)d_in[3];
  const float* b1 = (const float*)d_in[4];
  float* out = (float*)d_out;

  // ws layout (8 MiB + 8 KiB), regions reused across lifetimes:
  // [0,4M):   h (gemms) -> S fp64 (scans) -> A4 @0 (2M) + Cstk @2M (256K, after ds_mat)
  // [4M,6M):  z (1M) + norms (8K) -> A (2M)
  // [6M,8M):  D (2M) -> A2 (2M)
  // [8M,+8K): C0b
  char* base = (char*)d_ws;
  float*  h    = (float*)(base);
  double* S    = (double*)(base);
  float*  A4   = (float*)(base);
  float*  Cstk = (float*)(base + (2u << 20));
  float*  z    = (float*)(base + (4u << 20));
  float*  norms= (float*)(base + (5u << 20));
  float*  A    = (float*)(base + (4u << 20));
  float*  D    = (float*)(base + (6u << 20));
  float*  A2   = (float*)(base + (6u << 20));
  float*  C0b  = (float*)(base + (8u << 20));

  gemm_bias_act<<<dim3(F1/32, ROWS/64), 256, 0, stream>>>(x, W0, b0, h, ROWS, F1, F0, 1);
  gemm_bias_act<<<dim3(F2/32, ROWS/64), 256, 0, stream>>>(h, W1, b1, z, ROWS, F2, F1, 0);
  row_norms<<<dim3(ROWS*64/256), 256, 0, stream>>>(z, norms);
  corr_dist<<<dim3(NN/64, NN/64, NB), 256, 0, stream>>>(z, norms, D);
  rowscan<<<dim3(ROWS/4), 256, 0, stream>>>(D, S);
  colscan<<<dim3(NB*4), 64, 0, stream>>>(S);
  ds_mat<<<dim3(NB), 1024, 0, stream>>>(S, A, C0b);
  mp_mm<<<dim3(NN/64, NN/64, NB), 256, 0, stream>>>(A, A, A2);
  mp_mm<<<dim3(NN/64, NN/64, NB), 256, 0, stream>>>(A2, A2, A4);
  out_init_c0<<<dim3(ROWS/256), 256, 0, stream>>>(C0b, Cstk, out);
  chain_step<1><<<dim3(4, NB), 256, 0, stream>>>(A,  Cstk, 0, 1);
  chain_step<2><<<dim3(4, NB), 256, 0, stream>>>(A2, Cstk, 0, 2);
  for (int t = 0; t < 7; t++)
    chain_step<4><<<dim3(4, NB), 256, 0, stream>>>(A4, Cstk, 4*t, 4*t + 4);
  softmax_acc<<<dim3(KMAX-1, NB), 256, 0, stream>>>(A, Cstk, out);
}

// Round 4
// 303.498 us; speedup vs baseline: 1.5233x; 1.0721x over previous
//
#include <hip/hip_runtime.h>

constexpr int NB    = 8;     // batches
constexpr int NN    = 256;   // sequence length
constexpr int F0    = 512;
constexpr int F1    = 256;
constexpr int F2    = 128;
constexpr int ROWS  = NB * NN;   // 2048
constexpr int KMAX  = 30;
constexpr float INF = 1e30f;

// ---------------- fp32 GEMM: C = act(A @ B + bias), 64x32 tile, BK=16 ----------
__global__ __launch_bounds__(256) void gemm_bias_act(
    const float* __restrict__ A, const float* __restrict__ B,
    const float* __restrict__ bias, float* __restrict__ C,
    int M, int Ncols, int K, int relu)
{
  __shared__ float As[16][64];   // [k][m]
  __shared__ float Bs[16][32];   // [k][n]
  const int tid = threadIdx.x;
  const int tx = tid & 15;       // col group  (2 cols)
  const int ty = tid >> 4;       // row group  (4 rows)
  const int rowBase = blockIdx.y * 64;
  const int colBase = blockIdx.x * 32;
  float acc[4][2] = {};
  for (int k0 = 0; k0 < K; k0 += 16) {
    {
      const int r  = tid >> 2;
      const int kq = (tid & 3) << 2;
      const float4 av = *(const float4*)(A + (size_t)(rowBase + r) * K + (k0 + kq));
      As[kq+0][r] = av.x; As[kq+1][r] = av.y; As[kq+2][r] = av.z; As[kq+3][r] = av.w;
      const int kr = tid >> 4;
      const int c2 = (tid & 15) << 1;
      const float2 bv = *(const float2*)(B + (size_t)(k0 + kr) * Ncols + (colBase + c2));
      Bs[kr][c2+0] = bv.x; Bs[kr][c2+1] = bv.y;
    }
    __syncthreads();
    #pragma unroll
    for (int kk = 0; kk < 16; kk++) {
      const float4 a = *(const float4*)&As[kk][ty*4];
      const float b0v = Bs[kk][tx*2+0];
      const float b1v = Bs[kk][tx*2+1];
      acc[0][0] += a.x*b0v; acc[0][1] += a.x*b1v;
      acc[1][0] += a.y*b0v; acc[1][1] += a.y*b1v;
      acc[2][0] += a.z*b0v; acc[2][1] += a.z*b1v;
      acc[3][0] += a.w*b0v; acc[3][1] += a.w*b1v;
    }
    __syncthreads();
  }
  #pragma unroll
  for (int i = 0; i < 4; i++) {
    const int rr = rowBase + ty*4 + i;
    #pragma unroll
    for (int j = 0; j < 2; j++) {
      const int cc = colBase + tx*2 + j;
      float v = acc[i][j] + bias[cc];
      if (relu) v = fmaxf(v, 0.0f);
      C[(size_t)rr * Ncols + cc] = v;
    }
  }
}

// ---------------- row norms: norms[r] = ||z_r||^2, one wave per row ------------
__global__ __launch_bounds__(256) void row_norms(
    const float* __restrict__ z, float* __restrict__ norms)
{
  const int wave = (blockIdx.x * blockDim.x + threadIdx.x) >> 6;
  const int lane = threadIdx.x & 63;
  if (wave >= ROWS) return;
  const float* p = z + (size_t)wave * F2;
  float a = p[lane], b = p[lane + 64];
  float v = a*a + b*b;
  #pragma unroll
  for (int d = 32; d; d >>= 1) v += __shfl_xor(v, d);
  if (lane == 0) norms[wave] = v;
}

// ---------------- D[b,n,m] = 0.5*(1 - (z_n.z_m)/sqrt(max(|z_n|^2|z_m|^2,1e-8)))
__global__ __launch_bounds__(256) void corr_dist(
    const float* __restrict__ z, const float* __restrict__ norms,
    float* __restrict__ D)
{
  const int b = blockIdx.z;
  const float* zb = z + (size_t)b * NN * F2;
  __shared__ float As[16][64];  // [k][row]
  __shared__ float Bs[16][64];  // [k][col]
  const int tid = threadIdx.x;
  const int tx = tid & 15;
  const int ty = tid >> 4;
  const int rowBase = blockIdx.y * 64;
  const int colBase = blockIdx.x * 64;
  float acc[4][4] = {};
  for (int k0 = 0; k0 < F2; k0 += 16) {
    {
      const int r  = tid >> 2;
      const int kq = (tid & 3) << 2;
      const float4 av = *(const float4*)(zb + (size_t)(rowBase + r) * F2 + (k0 + kq));
      As[kq+0][r] = av.x; As[kq+1][r] = av.y; As[kq+2][r] = av.z; As[kq+3][r] = av.w;
      const float4 bv = *(const float4*)(zb + (size_t)(colBase + r) * F2 + (k0 + kq));
      Bs[kq+0][r] = bv.x; Bs[kq+1][r] = bv.y; Bs[kq+2][r] = bv.z; Bs[kq+3][r] = bv.w;
    }
    __syncthreads();
    #pragma unroll
    for (int kk = 0; kk < 16; kk++) {
      const float4 a = *(const float4*)&As[kk][ty*4];
      const float4 bq = *(const float4*)&Bs[kk][tx*4];
      const float ar[4] = {a.x, a.y, a.z, a.w};
      const float br[4] = {bq.x, bq.y, bq.z, bq.w};
      #pragma unroll
      for (int i = 0; i < 4; i++)
        #pragma unroll
        for (int j = 0; j < 4; j++)
          acc[i][j] += ar[i] * br[j];
    }
    __syncthreads();
  }
  float* Db = D + (size_t)b * NN * NN;
  #pragma unroll
  for (int i = 0; i < 4; i++) {
    const int rr = rowBase + ty*4 + i;
    const float nr = norms[b*NN + rr];
    #pragma unroll
    for (int j = 0; j < 4; j++) {
      const int cc = colBase + tx*4 + j;
      const float nc = norms[b*NN + cc];
      const float denom = sqrtf(fmaxf(nr * nc, 1e-8f));
      Db[(size_t)rr * NN + cc] = 0.5f * (1.0f - acc[i][j] / denom);
    }
  }
}

// ---------------- row-wise fp64 inclusive scan: one wave per row ----------------
__global__ __launch_bounds__(256) void rowscan(
    const float* __restrict__ D, double* __restrict__ S)
{
  const int r = blockIdx.x * 4 + (threadIdx.x >> 6);   // 2048 rows
  const int lane = threadIdx.x & 63;
  const float4 dv = *(const float4*)(D + (size_t)r * NN + lane * 4);
  double d0 = dv.x, d1 = dv.y, d2 = dv.z, d3 = dv.w;
  double p0 = d0, p1 = p0 + d1, p2 = p1 + d2, p3 = p2 + d3;  // local inclusive
  double t = p3;
  #pragma unroll
  for (int d = 1; d < 64; d <<= 1) {
    double u = __shfl_up(t, d);
    if (lane >= d) t += u;
  }
  const double off = t - p3;                 // exclusive prefix of lane totals
  double* srow = S + (size_t)r * NN + lane * 4;
  srow[0] = off + p0; srow[1] = off + p1; srow[2] = off + p2; srow[3] = off + p3;
}

// ---------------- column-wise fp64 scan (in place): 32 blocks x 64 thr ---------
__global__ __launch_bounds__(64) void colscan(double* __restrict__ S)
{
  const int b  = blockIdx.x >> 2;
  const int j  = (blockIdx.x & 3) * 64 + threadIdx.x;
  double* p = S + (size_t)b * NN * NN + j;
  double sum = 0.0;
  for (int r = 0; r < NN; r += 8) {
    double v0 = p[(size_t)(r+0)*NN], v1 = p[(size_t)(r+1)*NN];
    double v2 = p[(size_t)(r+2)*NN], v3 = p[(size_t)(r+3)*NN];
    double v4 = p[(size_t)(r+4)*NN], v5 = p[(size_t)(r+5)*NN];
    double v6 = p[(size_t)(r+6)*NN], v7 = p[(size_t)(r+7)*NN];
    v0 += sum; v1 += v0; v2 += v1; v3 += v2; v4 += v3; v5 += v4; v6 += v5; v7 += v6;
    p[(size_t)(r+0)*NN] = v0; p[(size_t)(r+1)*NN] = v1;
    p[(size_t)(r+2)*NN] = v2; p[(size_t)(r+3)*NN] = v3;
    p[(size_t)(r+4)*NN] = v4; p[(size_t)(r+5)*NN] = v5;
    p[(size_t)(r+6)*NN] = v6; p[(size_t)(r+7)*NN] = v7;
    sum = v7;
  }
}

// ---------------- Ds -> A (shifted), C0 -> Cstk[0], out init -------------------
// Ds[n,j] (j>=n) = S[j][j] - 2*S[n-1][j] + S[n-1][n-1];  A[n][j+1] = Ds[n][j]
// A[n][0] = INF;  Cstk[0][n] = Ds[n][N-1];  out[b][j] = (j==N-1)
__global__ __launch_bounds__(1024) void ds_mat(
    const double* __restrict__ S, float* __restrict__ A,
    float* __restrict__ Cstk, float* __restrict__ out)
{
  const int b = blockIdx.x;
  const double* Sb = S + (size_t)b * NN * NN;
  float* Ab = A + (size_t)b * NN * NN;
  const int tid = threadIdx.x;
  const int w = tid >> 6, lane = tid & 63;
  __shared__ double diag[NN];
  __shared__ float c0sh[NN];
  if (tid < NN) diag[tid] = Sb[(size_t)tid * NN + tid];
  __syncthreads();
  for (int t = 0; t < 16; t++) {
    const int n = w * 16 + t;
    const double snn = (n > 0) ? diag[n-1] : 0.0;
    const double* srow = Sb + (size_t)(n > 0 ? n-1 : 0) * NN;
    #pragma unroll
    for (int c = 0; c < 4; c++) {
      const int j = c * 64 + lane;
      float ds = INF;
      if (j >= n) {
        const double sv = (n > 0) ? srow[j] : 0.0;
        ds = (float)(diag[j] - 2.0 * sv + snn);
      }
      if (j < NN - 1) Ab[(size_t)n * NN + j + 1] = ds;
      else            c0sh[n] = ds;              // Ds[n][N-1]
      if (j == 0)     Ab[(size_t)n * NN + 0] = INF;
    }
  }
  __syncthreads();
  if (tid < NN) {
    Cstk[(size_t)b * 32 * NN + tid] = c0sh[tid];
    out[b * NN + tid] = (tid == NN - 1) ? 1.0f : 0.0f;
  }
}

// ---------------- min-plus MM: C = P (x) Q, 64x64 tile, per batch --------------
// P, Q strictly upper triangular (INF below): skip lower tiles + clamp k range.
__global__ __launch_bounds__(256) void mp_mm(
    const float* __restrict__ P, const float* __restrict__ Q, float* __restrict__ Cm)
{
  const int b = blockIdx.z;
  const int tid = threadIdx.x;
  const int tx = tid & 15;
  const int ty = tid >> 4;
  const int rowBase = blockIdx.y * 64;
  const int colBase = blockIdx.x * 64;
  float* Cb = Cm + (size_t)b * NN * NN;
  if (colBase < rowBase) {             // strictly-lower tile: all INF
    #pragma unroll
    for (int i = 0; i < 4; i++)
      #pragma unroll
      for (int j = 0; j < 4; j++)
        Cb[(size_t)(rowBase + ty*4 + i) * NN + (colBase + tx*4 + j)] = INF;
    return;
  }
  const float* Pb = P + (size_t)b * NN * NN;
  const float* Qb = Q + (size_t)b * NN * NN;
  __shared__ float As[16][64];
  __shared__ float Bs[16][64];
  float acc[4][4];
  #pragma unroll
  for (int i = 0; i < 4; i++)
    #pragma unroll
    for (int j = 0; j < 4; j++) acc[i][j] = INF;
  const int kHi = (colBase + 64 < NN) ? colBase + 64 : NN;
  for (int k0 = rowBase; k0 < kHi; k0 += 16) {
    {
      const int r  = tid >> 2;
      const int kq = (tid & 3) << 2;
      const float4 av = *(const float4*)(Pb + (size_t)(rowBase + r) * NN + (k0 + kq));
      As[kq+0][r] = av.x; As[kq+1][r] = av.y; As[kq+2][r] = av.z; As[kq+3][r] = av.w;
      const int kr = tid >> 4;
      const int c4 = (tid & 15) << 2;
      const float4 bv = *(const float4*)(Qb + (size_t)(k0 + kr) * NN + (colBase + c4));
      Bs[kr][c4+0] = bv.x; Bs[kr][c4+1] = bv.y; Bs[kr][c4+2] = bv.z; Bs[kr][c4+3] = bv.w;
    }
    __syncthreads();
    #pragma unroll
    for (int kk = 0; kk < 16; kk++) {
      const float4 a = *(const float4*)&As[kk][ty*4];
      const float4 bq = *(const float4*)&Bs[kk][tx*4];
      const float ar[4] = {a.x, a.y, a.z, a.w};
      const float br[4] = {bq.x, bq.y, bq.z, bq.w};
      #pragma unroll
      for (int i = 0; i < 4; i++)
        #pragma unroll
        for (int j = 0; j < 4; j++)
          acc[i][j] = fminf(acc[i][j], ar[i] + br[j]);
    }
    __syncthreads();
  }
  #pragma unroll
  for (int i = 0; i < 4; i++)
    #pragma unroll
    for (int j = 0; j < 4; j++)
      Cb[(size_t)(rowBase + ty*4 + i) * NN + (colBase + tx*4 + j)] =
          fminf(acc[i][j], INF);
}

// ---------------- full chain C_1..C_29 in one kernel: 1 block/batch ------------
constexpr int CSTR = 260;   // LDS stride: 16B-aligned, breaks pow2 banks

template<int W>
__device__ __forceinline__ void mp_stage(
    const float* __restrict__ P, size_t mb, int n, int q,
    const float* cs, int kin, float* outm)
{
  const float* Pr = P + mb + (size_t)n * NN + q * 64;
  float m[W];
  #pragma unroll
  for (int v = 0; v < W; v++) m[v] = INF;
  if (q * 64 + 63 > n) {          // chunk contains some j > n (else all INF)
    #pragma unroll 4
    for (int i = 0; i < 16; i++) {
      const float4 a = *(const float4*)(Pr + i * 4);
      #pragma unroll
      for (int v = 0; v < W; v++) {
        const float4 c = *(const float4*)&cs[(kin + v) * CSTR + q * 64 + i * 4];
        m[v] = fminf(m[v], fminf(fminf(a.x + c.x, a.y + c.y),
                                 fminf(a.z + c.z, a.w + c.w)));
      }
    }
  }
  #pragma unroll
  for (int v = 0; v < W; v++) {
    m[v] = fminf(m[v], __shfl_xor(m[v], 1));
    m[v] = fminf(m[v], __shfl_xor(m[v], 2));
    outm[v] = fminf(m[v], INF);
  }
}

__global__ __launch_bounds__(1024) void chain_full(
    const float* __restrict__ A, const float* __restrict__ A2,
    const float* __restrict__ A4, float* __restrict__ Cstk)
{
  const int b = blockIdx.x;
  const int tid = threadIdx.x;
  const int n = tid >> 2, q = tid & 3;
  __shared__ __align__(16) float cs[32 * CSTR];
  float* Ck = Cstk + (size_t)b * 32 * NN;
  if (tid < NN) cs[0 * CSTR + tid] = Ck[tid];
  __syncthreads();
  const size_t mb = (size_t)b * NN * NN;

  float m1[1];
  mp_stage<1>(A, mb, n, q, cs, 0, m1);
  if (q == 0) { cs[1*CSTR + n] = m1[0]; Ck[1*NN + n] = m1[0]; }
  __syncthreads();

  float m2[2];
  mp_stage<2>(A2, mb, n, q, cs, 0, m2);
  if (q == 0) {
    cs[2*CSTR + n] = m2[0]; Ck[2*NN + n] = m2[0];
    cs[3*CSTR + n] = m2[1]; Ck[3*NN + n] = m2[1];
  }
  __syncthreads();

  for (int t = 0; t < 7; t++) {
    float m4[4];
    mp_stage<4>(A4, mb, n, q, cs, 4*t, m4);
    if (q == 0) {
      #pragma unroll
      for (int v = 0; v < 4; v++) {
        cs[(4*t + 4 + v)*CSTR + n] = m4[v];
        Ck[(4*t + 4 + v)*NN + n]  = m4[v];
      }
    }
    __syncthreads();
  }
}

// ---------------- softmax pass 1: row sums (coalesced float4) ------------------
// s_n = sum_{jj=n+1}^{limit} exp(C_k[n] - A[n][jj] - C_{k-1}[jj]); invs = 1/s
// (jj <= n terms auto-zero via A INF; only jj <= limit mask is explicit)
__global__ __launch_bounds__(256) void sm_rows(
    const float* __restrict__ A, const float* __restrict__ Cstk,
    float* __restrict__ invs)
{
  const int rg = blockIdx.x;          // row group 0..3
  const int k  = blockIdx.y + 1;      // 1..29
  const int b  = blockIdx.z;
  const int limit = NN - k;
  const int tid = threadIdx.x;
  const int r = tid >> 2, q = tid & 3;
  const int n = rg * 64 + r;
  __shared__ __align__(16) float cprev[NN];
  __shared__ float ck[NN];
  const float* Ckb = Cstk + (size_t)b * 32 * NN;
  cprev[tid] = Ckb[(k - 1) * NN + tid];
  ck[tid]    = Ckb[k * NN + tid];
  __syncthreads();
  const float m = ck[n];
  const float* Ar = A + (size_t)b * NN * NN + (size_t)n * NN + q * 64;
  float s = 0.f;
  if (q * 64 + 63 > n) {              // chunk has some jj > n
    #pragma unroll 4
    for (int i = 0; i < 16; i++) {
      const float4 a = *(const float4*)(Ar + i * 4);
      const int jj = q * 64 + i * 4;
      const float4 c = *(const float4*)&cprev[jj];
      s += (jj + 0 <= limit) ? __expf(m - a.x - c.x) : 0.f;
      s += (jj + 1 <= limit) ? __expf(m - a.y - c.y) : 0.f;
      s += (jj + 2 <= limit) ? __expf(m - a.z - c.z) : 0.f;
      s += (jj + 3 <= limit) ? __expf(m - a.w - c.w) : 0.f;
    }
  }
  s += __shfl_xor(s, 1);
  s += __shfl_xor(s, 2);
  if (q == 0) invs[((size_t)b * 32 + k) * NN + n] = 1.0f / s;
}

// ---------------- softmax pass 2: column accumulation (coalesced) --------------
__global__ __launch_bounds__(256) void sm_cols(
    const float* __restrict__ A, const float* __restrict__ Cstk,
    const float* __restrict__ invs, float* __restrict__ out)
{
  const int k = blockIdx.x + 1;        // 1..29
  const int b = blockIdx.y;
  const int limit = NN - k;
  const int tid = threadIdx.x;
  const float* Ab = A + (size_t)b * NN * NN;
  const float* Ckb = Cstk + (size_t)b * 32 * NN;
  __shared__ float csh[NN];    // C_{k-1}[j+1]
  __shared__ float mrow[NN];   // C_k[n]
  __shared__ float ivh[NN];
  csh[tid]  = (tid < NN - 1) ? Ckb[(k - 1) * NN + tid + 1] : 0.0f;
  mrow[tid] = Ckb[k * NN + tid];
  ivh[tid]  = invs[((size_t)b * 32 + k) * NN + tid];
  __syncthreads();
  const int j = tid;
  if (j < limit) {
    const float cj = csh[j];
    const int nmax = (j < limit - 1) ? j : limit - 1;
    float a = 0.0f;
    for (int nr = 0; nr <= nmax; nr++)
      a += __expf(mrow[nr] - Ab[(size_t)nr * NN + j + 1] - cj) * ivh[nr];
    int kmaxj = NN - 1 - j; if (kmaxj > KMAX - 1) kmaxj = KMAX - 1;
    const float cnt = (float)((j + 1) * kmaxj);
    atomicAdd(&out[b * NN + j], a / cnt);
  }
}

extern "C" void kernel_launch(void* const* d_in, const int* in_sizes, int n_in,
                              void* d_out, int out_size, void* d_ws, size_t ws_size,
                              hipStream_t stream) {
  const float* x  = (const float*)d_in[0];
  const float* W0 = (const float*)d_in[1];
  const float* b0 = (const float*)d_in[2];
  const float* W1 = (const float*)d_in[3];
  const float* b1 = (const float*)d_in[4];
  float* out = (float*)d_out;

  // ws layout (max 7 MiB + 8 KiB used; ws proven >= 8 MiB + 8 KiB):
  //  region        lifetime
  //  h    [0,2M)   gemm1 W -> gemm2 R
  //  S    [0,4M)   rowscan W (h dead) -> colscan RW -> ds_mat R
  //  A2   [0,2M)   mp_mm1 W (S dead) -> mp_mm2/chain R
  //  A4   [2M,4M)  mp_mm2 W -> chain R
  //  D    [4M,6M)  corr_dist W -> rowscan R
  //  A    [4M,6M)  ds_mat W (D dead) -> mp_mm1/chain/sm R
  //  z    [6M,7M)  gemm2 W -> row_norms/corr_dist R
  //  Cstk [6M,6.25M) ds_mat W (z dead) -> chain RW -> sm R
  //  invs [6.5M,6.75M) sm_rows W -> sm_cols R
  //  norms[7M,+8K) row_norms W -> corr_dist R
  char* base = (char*)d_ws;
  float*  h    = (float*)(base);
  double* S    = (double*)(base);
  float*  A2   = (float*)(base);
  float*  A4   = (float*)(base + (2u << 20));
  float*  D    = (float*)(base + (4u << 20));
  float*  A    = (float*)(base + (4u << 20));
  float*  z    = (float*)(base + (6u << 20));
  float*  Cstk = (float*)(base + (6u << 20));
  float*  invs = (float*)(base + (6u << 20) + (512u << 10));
  float*  norms= (float*)(base + (7u << 20));

  gemm_bias_act<<<dim3(F1/32, ROWS/64), 256, 0, stream>>>(x, W0, b0, h, ROWS, F1, F0, 1);
  gemm_bias_act<<<dim3(F2/32, ROWS/64), 256, 0, stream>>>(h, W1, b1, z, ROWS, F2, F1, 0);
  row_norms<<<dim3(ROWS*64/256), 256, 0, stream>>>(z, norms);
  corr_dist<<<dim3(NN/64, NN/64, NB), 256, 0, stream>>>(z, norms, D);
  rowscan<<<dim3(ROWS/4), 256, 0, stream>>>(D, S);
  colscan<<<dim3(NB*4), 64, 0, stream>>>(S);
  ds_mat<<<dim3(NB), 1024, 0, stream>>>(S, A, Cstk, out);
  mp_mm<<<dim3(NN/64, NN/64, NB), 256, 0, stream>>>(A, A, A2);
  mp_mm<<<dim3(NN/64, NN/64, NB), 256, 0, stream>>>(A2, A2, A4);
  chain_full<<<dim3(NB), 1024, 0, stream>>>(A, A2, A4, Cstk);
  sm_rows<<<dim3(4, KMAX-1, NB), 256, 0, stream>>>(A, Cstk, invs);
  sm_cols<<<dim3(KMAX-1, NB), 256, 0, stream>>>(A, Cstk, invs, out);
}